// Round 2
// baseline (97.826 us; speedup 1.0000x reference)
//
#include <hip/hip_runtime.h>

#define D_DIM 1280
#define ODIM  510
#define BD    128
#define TILE  32
#define LROWF 132   // floats: 528 B row stride — 16B aligned, 4-word bank shift/row

// out[i-1][j-1][k] = b[k] + sum_d X[i,d] * X[j,d] * W[d][k],  i,j in [1,510], k in {0,1}
// (the antisymmetric d_proj/diff term cancels exactly under the (P + P^T)/2 symmetrization)
__global__ __launch_bounds__(256, 1) void pcmd_kernel(
    const float* __restrict__ X,   // [512][1280] fp32
    const float* __restrict__ W,   // [2560][2]   fp32 (first 1280 rows = Wp)
    const float* __restrict__ b,   // [2]         fp32
    float* __restrict__ out)       // [510][510][2] fp32
{
  __shared__ float sXi[TILE * LROWF];
  __shared__ float sXj[TILE * LROWF];
  __shared__ float sW[BD * 2];     // (w0,w1) interleaved per d

  const int tid = threadIdx.x;
  const int tx  = tid & 15;        // j within tile
  const int ty  = tid >> 4;        // i within tile
  const int i_base = 1 + (int)blockIdx.y * TILE;
  const int j_base = 1 + (int)blockIdx.x * TILE;

  float acc[2][2][2] = {};         // [ii][jj][k]

  const float* pi0 = sXi + ty * LROWF;
  const float* pi1 = sXi + (ty + 16) * LROWF;
  const float* pj0 = sXj + tx * LROWF;
  const float* pj1 = sXj + (tx + 16) * LROWF;

  for (int d0 = 0; d0 < D_DIM; d0 += BD) {
    __syncthreads();               // protect LDS reuse across chunks

    // stage 32 rows x 128 floats per side: 1024 float4 chunks, 4 per thread per side
    #pragma unroll
    for (int c0 = 0; c0 < 4; ++c0) {
      int c   = tid + c0 * 256;
      int r   = c >> 5;            // row 0..31
      int off = (c & 31) << 2;     // float offset 0..124
      int gi = i_base + r; if (gi > 511) gi = 511;   // clamp; masked at store
      int gj = j_base + r; if (gj > 511) gj = 511;
      float4 vi = *(const float4*)(X + (size_t)gi * D_DIM + d0 + off);
      float4 vj = *(const float4*)(X + (size_t)gj * D_DIM + d0 + off);
      *(float4*)(sXi + r * LROWF + off) = vi;
      *(float4*)(sXj + r * LROWF + off) = vj;
    }
    if (tid < BD) {
      int d = d0 + tid;
      sW[2 * tid]     = W[2 * d];
      sW[2 * tid + 1] = W[2 * d + 1];
    }
    __syncthreads();

    #pragma unroll 2
    for (int d = 0; d < BD; d += 4) {
      float4 xi0 = *(const float4*)(pi0 + d);
      float4 xi1 = *(const float4*)(pi1 + d);
      float4 xj0 = *(const float4*)(pj0 + d);
      float4 xj1 = *(const float4*)(pj1 + d);
      float4 wA = *(const float4*)(sW + 2 * d);      // w0[d],w1[d],w0[d+1],w1[d+1]
      float4 wB = *(const float4*)(sW + 2 * d + 4);  // w0[d+2],w1[d+2],w0[d+3],w1[d+3]

      float t;
      // d+0
      t = xi0.x * xj0.x; acc[0][0][0] = fmaf(t, wA.x, acc[0][0][0]); acc[0][0][1] = fmaf(t, wA.y, acc[0][0][1]);
      t = xi0.x * xj1.x; acc[0][1][0] = fmaf(t, wA.x, acc[0][1][0]); acc[0][1][1] = fmaf(t, wA.y, acc[0][1][1]);
      t = xi1.x * xj0.x; acc[1][0][0] = fmaf(t, wA.x, acc[1][0][0]); acc[1][0][1] = fmaf(t, wA.y, acc[1][0][1]);
      t = xi1.x * xj1.x; acc[1][1][0] = fmaf(t, wA.x, acc[1][1][0]); acc[1][1][1] = fmaf(t, wA.y, acc[1][1][1]);
      // d+1
      t = xi0.y * xj0.y; acc[0][0][0] = fmaf(t, wA.z, acc[0][0][0]); acc[0][0][1] = fmaf(t, wA.w, acc[0][0][1]);
      t = xi0.y * xj1.y; acc[0][1][0] = fmaf(t, wA.z, acc[0][1][0]); acc[0][1][1] = fmaf(t, wA.w, acc[0][1][1]);
      t = xi1.y * xj0.y; acc[1][0][0] = fmaf(t, wA.z, acc[1][0][0]); acc[1][0][1] = fmaf(t, wA.w, acc[1][0][1]);
      t = xi1.y * xj1.y; acc[1][1][0] = fmaf(t, wA.z, acc[1][1][0]); acc[1][1][1] = fmaf(t, wA.w, acc[1][1][1]);
      // d+2
      t = xi0.z * xj0.z; acc[0][0][0] = fmaf(t, wB.x, acc[0][0][0]); acc[0][0][1] = fmaf(t, wB.y, acc[0][0][1]);
      t = xi0.z * xj1.z; acc[0][1][0] = fmaf(t, wB.x, acc[0][1][0]); acc[0][1][1] = fmaf(t, wB.y, acc[0][1][1]);
      t = xi1.z * xj0.z; acc[1][0][0] = fmaf(t, wB.x, acc[1][0][0]); acc[1][0][1] = fmaf(t, wB.y, acc[1][0][1]);
      t = xi1.z * xj1.z; acc[1][1][0] = fmaf(t, wB.x, acc[1][1][0]); acc[1][1][1] = fmaf(t, wB.y, acc[1][1][1]);
      // d+3
      t = xi0.w * xj0.w; acc[0][0][0] = fmaf(t, wB.z, acc[0][0][0]); acc[0][0][1] = fmaf(t, wB.w, acc[0][0][1]);
      t = xi0.w * xj1.w; acc[0][1][0] = fmaf(t, wB.z, acc[0][1][0]); acc[0][1][1] = fmaf(t, wB.w, acc[0][1][1]);
      t = xi1.w * xj0.w; acc[1][0][0] = fmaf(t, wB.z, acc[1][0][0]); acc[1][0][1] = fmaf(t, wB.w, acc[1][0][1]);
      t = xi1.w * xj1.w; acc[1][1][0] = fmaf(t, wB.z, acc[1][1][0]); acc[1][1][1] = fmaf(t, wB.w, acc[1][1][1]);
    }
  }

  const float b0 = b[0];
  const float b1 = b[1];

  #pragma unroll
  for (int ii = 0; ii < 2; ++ii) {
    int i = i_base + ty + ii * 16;
    if (i > ODIM) continue;        // valid i: 1..510
    #pragma unroll
    for (int jj = 0; jj < 2; ++jj) {
      int j = j_base + tx + jj * 16;
      if (j > ODIM) continue;
      float2 v;
      v.x = acc[ii][jj][0] + b0;
      v.y = acc[ii][jj][1] + b1;
      *(float2*)(out + ((size_t)(i - 1) * ODIM + (j - 1)) * 2) = v;
    }
  }
}

extern "C" void kernel_launch(void* const* d_in, const int* in_sizes, int n_in,
                              void* d_out, int out_size, void* d_ws, size_t ws_size,
                              hipStream_t stream) {
  const float* X = (const float*)d_in[0];  // prev_result fp32 [1][512][1280]
  const float* W = (const float*)d_in[1];  // W fp32 [2560][2]
  const float* b = (const float*)d_in[2];  // b fp32 [2]
  float* out = (float*)d_out;              // [1][510][510][2] fp32
  dim3 grid(16, 16, 1);                    // ceil(510/32) = 16 tiles each dim
  dim3 block(256, 1, 1);
  hipLaunchKernelGGL(pcmd_kernel, grid, block, 0, stream, X, W, b, out);
}

// Round 3
// 77.528 us; speedup vs baseline: 1.2618x; 1.2618x over previous
//
#include <hip/hip_runtime.h>

#define D_DIM 1280
#define ODIM  510
#define KC    128           // d-chunk per LDS stage
#define NCH   (D_DIM / KC)  // 10 chunks
#define TILE  32
#define LROW  136           // bf16 units: 272 B row stride (16B-aligned, 4-bank shift/row)

typedef __attribute__((ext_vector_type(8))) short bf16x8;  // 8 bf16 = 4 VGPRs
typedef __attribute__((ext_vector_type(4))) float f32x4;

// pack two fp32 -> two bf16 (round-half-up; |err| <= bf16 RNE + tiny, fine vs 0.085 tol)
__device__ __forceinline__ unsigned pkbf(float a, float b) {
  unsigned ua = __float_as_uint(a), ub = __float_as_uint(b);
  return ((ua + 0x8000u) >> 16) | ((ub + 0x8000u) & 0xffff0000u);
}

// out[i-1][j-1][k] = b[k] + sum_d X[i,d]*X[j,d]*W[d][k]  (antisym diff-term cancels)
__global__ __launch_bounds__(256, 1) void pcmd_mfma(
    const float* __restrict__ X,   // [512][1280]
    const float* __restrict__ W,   // [2560][2]  (first 1280 rows = Wp)
    const float* __restrict__ b,   // [2]
    float* __restrict__ out)       // [510][510][2]
{
  __shared__ unsigned short sA[TILE * LROW];       // bf16(X) i-rows
  __shared__ unsigned short sB[2][TILE * LROW];    // bf16(X*w_c) j-rows, per channel
  __shared__ float sW[2 * D_DIM];                  // W staged once, fp32

  const int tid  = threadIdx.x;
  const int lane = tid & 63;
  const int wv   = tid >> 6;       // wave 0..3
  const int cch  = wv & 1;         // output channel k
  const int ih   = wv >> 1;        // i-half (0: rows 0-15, 1: rows 16-31)
  const int m    = lane & 15;
  const int quad = lane >> 4;

  const int i_base = 1 + (int)blockIdx.y * TILE;
  const int j_base = 1 + (int)blockIdx.x * TILE;

  // staging mapping: thread -> (tile row, 16-float d-group)
  const int sr = tid & 31;
  const int sg = tid >> 5;         // 0..7

  int gi = i_base + sr; if (gi > 511) gi = 511;    // clamp; bad rows masked at store
  int gj = j_base + sr; if (gj > 511) gj = 511;
  const float* pA = X + (size_t)gi * D_DIM + sg * 16;
  const float* pB = X + (size_t)gj * D_DIM + sg * 16;

  // stage all of W into LDS (2560 floats, coalesced)
  for (int k = tid; k < 2 * D_DIM; k += 256) sW[k] = W[k];

  // prefetch chunk 0
  float4 ra[4], rb[4];
  #pragma unroll
  for (int q = 0; q < 4; ++q) {
    ra[q] = *(const float4*)(pA + 4 * q);
    rb[q] = *(const float4*)(pB + 4 * q);
  }

  f32x4 acc0 = {0.f, 0.f, 0.f, 0.f};   // j-tile 0 (cols j_base..+15)
  f32x4 acc1 = {0.f, 0.f, 0.f, 0.f};   // j-tile 1 (cols j_base+16..+31)

  for (int c = 0; c < NCH; ++c) {
    __syncthreads();   // c=0: sW ready; c>0: prev compute done reading LDS

    // ---- pack + store chunk c (regs -> LDS) ----
    {
      unsigned short* dst = sA + sr * LROW + sg * 16;
      uint4 v0, v1;
      v0.x = pkbf(ra[0].x, ra[0].y); v0.y = pkbf(ra[0].z, ra[0].w);
      v0.z = pkbf(ra[1].x, ra[1].y); v0.w = pkbf(ra[1].z, ra[1].w);
      v1.x = pkbf(ra[2].x, ra[2].y); v1.y = pkbf(ra[2].z, ra[2].w);
      v1.z = pkbf(ra[3].x, ra[3].y); v1.w = pkbf(ra[3].z, ra[3].w);
      *(uint4*)dst = v0;
      *(uint4*)(dst + 8) = v1;
    }
    {
      const float* wp = sW + 2 * (c * KC + sg * 16);  // 32 floats: (w0,w1) x16 d's
      float4 wq0 = *(const float4*)(wp +  0);   // w0[0],w1[0],w0[1],w1[1]
      float4 wq1 = *(const float4*)(wp +  4);
      float4 wq2 = *(const float4*)(wp +  8);
      float4 wq3 = *(const float4*)(wp + 12);
      float4 wq4 = *(const float4*)(wp + 16);
      float4 wq5 = *(const float4*)(wp + 20);
      float4 wq6 = *(const float4*)(wp + 24);
      float4 wq7 = *(const float4*)(wp + 28);

      unsigned short* d0 = sB[0] + sr * LROW + sg * 16;
      unsigned short* d1 = sB[1] + sr * LROW + sg * 16;
      uint4 u0, u1;
      // channel 0 (w = .x/.z of each pair-vector)
      u0.x = pkbf(rb[0].x * wq0.x, rb[0].y * wq0.z);
      u0.y = pkbf(rb[0].z * wq1.x, rb[0].w * wq1.z);
      u0.z = pkbf(rb[1].x * wq2.x, rb[1].y * wq2.z);
      u0.w = pkbf(rb[1].z * wq3.x, rb[1].w * wq3.z);
      u1.x = pkbf(rb[2].x * wq4.x, rb[2].y * wq4.z);
      u1.y = pkbf(rb[2].z * wq5.x, rb[2].w * wq5.z);
      u1.z = pkbf(rb[3].x * wq6.x, rb[3].y * wq6.z);
      u1.w = pkbf(rb[3].z * wq7.x, rb[3].w * wq7.z);
      *(uint4*)d0 = u0;
      *(uint4*)(d0 + 8) = u1;
      // channel 1 (w = .y/.w)
      u0.x = pkbf(rb[0].x * wq0.y, rb[0].y * wq0.w);
      u0.y = pkbf(rb[0].z * wq1.y, rb[0].w * wq1.w);
      u0.z = pkbf(rb[1].x * wq2.y, rb[1].y * wq2.w);
      u0.w = pkbf(rb[1].z * wq3.y, rb[1].w * wq3.w);
      u1.x = pkbf(rb[2].x * wq4.y, rb[2].y * wq4.w);
      u1.y = pkbf(rb[2].z * wq5.y, rb[2].w * wq5.w);
      u1.z = pkbf(rb[3].x * wq6.y, rb[3].y * wq6.w);
      u1.w = pkbf(rb[3].z * wq7.y, rb[3].w * wq7.w);
      *(uint4*)d1 = u0;
      *(uint4*)(d1 + 8) = u1;
    }
    __syncthreads();

    // ---- prefetch chunk c+1 (independent of LDS; overlaps compute) ----
    if (c + 1 < NCH) {
      int off = (c + 1) * KC;
      #pragma unroll
      for (int q = 0; q < 4; ++q) {
        ra[q] = *(const float4*)(pA + off + 4 * q);
        rb[q] = *(const float4*)(pB + off + 4 * q);
      }
    }

    // ---- MFMA over chunk c: 4 K-steps of 32 ----
    // A layout: A[m = lane&15][k = quad*8 + j]  (verified m120)
    // B operand: B[n = lane&15][k = quad*8 + j] on the [j][d] tile
    const unsigned short* fa  = sA + (ih * 16 + m) * LROW + quad * 8;
    const unsigned short* fb0 = sB[cch] + m * LROW + quad * 8;
    const unsigned short* fb1 = sB[cch] + (16 + m) * LROW + quad * 8;
    #pragma unroll
    for (int ks = 0; ks < 4; ++ks) {
      bf16x8 af  = *(const bf16x8*)(fa  + ks * 32);
      bf16x8 bf0 = *(const bf16x8*)(fb0 + ks * 32);
      bf16x8 bf1 = *(const bf16x8*)(fb1 + ks * 32);
      acc0 = __builtin_amdgcn_mfma_f32_16x16x32_bf16(af, bf0, acc0, 0, 0, 0);
      acc1 = __builtin_amdgcn_mfma_f32_16x16x32_bf16(af, bf1, acc1, 0, 0, 0);
    }
  }

  // ---- epilogue: C/D layout col=lane&15, row=quad*4+reg (verified m89/m91) ----
  const float bias = b[cch];
  const int i0 = i_base + ih * 16 + quad * 4;
  const int j0 = j_base + m;
  #pragma unroll
  for (int r = 0; r < 4; ++r) {
    int i = i0 + r;
    if (i > ODIM) continue;
    if (j0 <= ODIM)
      out[((size_t)(i - 1) * ODIM + (j0 - 1)) * 2 + cch] = acc0[r] + bias;
    int j1 = j0 + 16;
    if (j1 <= ODIM)
      out[((size_t)(i - 1) * ODIM + (j1 - 1)) * 2 + cch] = acc1[r] + bias;
  }
}

extern "C" void kernel_launch(void* const* d_in, const int* in_sizes, int n_in,
                              void* d_out, int out_size, void* d_ws, size_t ws_size,
                              hipStream_t stream) {
  const float* X = (const float*)d_in[0];
  const float* W = (const float*)d_in[1];
  const float* b = (const float*)d_in[2];
  float* out = (float*)d_out;
  (void)d_ws; (void)ws_size; (void)in_sizes; (void)n_in; (void)out_size;
  dim3 grid(16, 16, 1);   // ceil(510/32)=16 each dim -> 256 blocks = 1/CU
  dim3 block(256, 1, 1);
  hipLaunchKernelGGL(pcmd_mfma, grid, block, 0, stream, X, W, b, out);
}

// Round 4
// 75.698 us; speedup vs baseline: 1.2923x; 1.0242x over previous
//
#include <hip/hip_runtime.h>

#define D_DIM 1280
#define ODIM  510
#define NSTEP (D_DIM / 32)   // 40 K-steps of 32

typedef __attribute__((ext_vector_type(8))) short bf16x8;  // 8 bf16 = 4 VGPRs
typedef __attribute__((ext_vector_type(4))) float f32x4;

// pack two fp32 -> packed bf16 pair (round-half-up)
__device__ __forceinline__ unsigned pkbf(float a, float b) {
  unsigned ua = __float_as_uint(a), ub = __float_as_uint(b);
  return ((ua + 0x8000u) >> 16) | ((ub + 0x8000u) & 0xffff0000u);
}

// Prep: Xbf = bf16(X), A0 = bf16(X*w0), A1 = bf16(X*w1).  81920 threads, 8 d's each.
__global__ __launch_bounds__(256, 1) void pcmd_prep(
    const float* __restrict__ X,        // [512][1280]
    const float* __restrict__ W,        // [2560][2] (first 1280 rows = Wp)
    unsigned short* __restrict__ Xbf,
    unsigned short* __restrict__ A0,
    unsigned short* __restrict__ A1)
{
  int t = (int)blockIdx.x * 256 + (int)threadIdx.x;   // 0..81919
  int r = t / 160;
  int c = t - r * 160;                  // 8-col group 0..159
  const float* px = X + (size_t)r * D_DIM + c * 8;
  float4 x0 = *(const float4*)px;
  float4 x1 = *(const float4*)(px + 4);
  const float* pw = W + (size_t)c * 16; // d=c*8 → W offset d*2
  float4 w0 = *(const float4*)(pw +  0);  // w0[d],w1[d],w0[d+1],w1[d+1]
  float4 w1 = *(const float4*)(pw +  4);
  float4 w2 = *(const float4*)(pw +  8);
  float4 w3 = *(const float4*)(pw + 12);
  size_t o = (size_t)r * D_DIM + c * 8;
  uint4 vx, v0, v1;
  vx.x = pkbf(x0.x, x0.y);            vx.y = pkbf(x0.z, x0.w);
  vx.z = pkbf(x1.x, x1.y);            vx.w = pkbf(x1.z, x1.w);
  v0.x = pkbf(x0.x*w0.x, x0.y*w0.z);  v0.y = pkbf(x0.z*w1.x, x0.w*w1.z);
  v0.z = pkbf(x1.x*w2.x, x1.y*w2.z);  v0.w = pkbf(x1.z*w3.x, x1.w*w3.z);
  v1.x = pkbf(x0.x*w0.y, x0.y*w0.w);  v1.y = pkbf(x0.z*w1.y, x0.w*w1.w);
  v1.z = pkbf(x1.x*w2.y, x1.y*w2.w);  v1.w = pkbf(x1.z*w3.y, x1.w*w3.w);
  *(uint4*)(Xbf + o) = vx;
  *(uint4*)(A0  + o) = v0;
  *(uint4*)(A1  + o) = v1;
}

// GEMM: one wave per 16x16 output tile, both channels; no LDS, no barriers.
// acc_k[i][j] = sum_d A_k[i,d] * Xbf[j,d]   (B^T-style operand, layout = A layout)
__global__ __launch_bounds__(256, 1) void pcmd_gemm(
    const unsigned short* __restrict__ Xbf,
    const unsigned short* __restrict__ A0,
    const unsigned short* __restrict__ A1,
    const float* __restrict__ b,
    float* __restrict__ out)            // [510][510][2]
{
  const int tid  = threadIdx.x;
  const int lane = tid & 63;
  const int wv   = tid >> 6;           // 4 waves: (wi,wj) 16x16 subtiles of 32x32
  const int wi   = wv >> 1;
  const int wj   = wv & 1;
  const int m    = lane & 15;
  const int quad = lane >> 4;

  const int i_base = 1 + (int)blockIdx.y * 32 + wi * 16;
  const int j_base = 1 + (int)blockIdx.x * 32 + wj * 16;
  int gi = i_base + m; if (gi > 511) gi = 511;   // clamp; masked at store
  int gj = j_base + m; if (gj > 511) gj = 511;

  const unsigned short* pa0 = A0  + (size_t)gi * D_DIM + quad * 8;
  const unsigned short* pa1 = A1  + (size_t)gi * D_DIM + quad * 8;
  const unsigned short* pb  = Xbf + (size_t)gj * D_DIM + quad * 8;

  // software pipeline, prefetch distance 4
  bf16x8 ra0[4], ra1[4], rb[4];
  #pragma unroll
  for (int s = 0; s < 4; ++s) {
    ra0[s] = *(const bf16x8*)(pa0 + s * 32);
    ra1[s] = *(const bf16x8*)(pa1 + s * 32);
    rb[s]  = *(const bf16x8*)(pb  + s * 32);
  }

  f32x4 acc0 = {0.f, 0.f, 0.f, 0.f};
  f32x4 acc1 = {0.f, 0.f, 0.f, 0.f};

  #pragma unroll 4
  for (int s = 0; s < NSTEP; ++s) {
    int cur = s & 3;
    bf16x8 a0 = ra0[cur], a1 = ra1[cur], bb = rb[cur];
    if (s + 4 < NSTEP) {
      ra0[cur] = *(const bf16x8*)(pa0 + (s + 4) * 32);
      ra1[cur] = *(const bf16x8*)(pa1 + (s + 4) * 32);
      rb[cur]  = *(const bf16x8*)(pb  + (s + 4) * 32);
    }
    acc0 = __builtin_amdgcn_mfma_f32_16x16x32_bf16(a0, bb, acc0, 0, 0, 0);
    acc1 = __builtin_amdgcn_mfma_f32_16x16x32_bf16(a1, bb, acc1, 0, 0, 0);
  }

  // C/D: col = lane&15 (j), row = quad*4 + reg (i)  [verified m89/m91]
  const float b0 = b[0], b1 = b[1];
  const int j = j_base + m;
  #pragma unroll
  for (int r = 0; r < 4; ++r) {
    int i = i_base + quad * 4 + r;
    if (i <= ODIM && j <= ODIM) {
      float2 v;
      v.x = acc0[r] + b0;
      v.y = acc1[r] + b1;
      *(float2*)(out + ((size_t)(i - 1) * ODIM + (j - 1)) * 2) = v;
    }
  }
}

extern "C" void kernel_launch(void* const* d_in, const int* in_sizes, int n_in,
                              void* d_out, int out_size, void* d_ws, size_t ws_size,
                              hipStream_t stream) {
  const float* X = (const float*)d_in[0];
  const float* W = (const float*)d_in[1];
  const float* b = (const float*)d_in[2];
  float* out = (float*)d_out;
  (void)in_sizes; (void)n_in; (void)out_size; (void)ws_size;

  const size_t PLANE = (size_t)512 * D_DIM;        // elements per bf16 plane
  unsigned short* Xbf = (unsigned short*)d_ws;     // 1.31 MB
  unsigned short* A0  = Xbf + PLANE;
  unsigned short* A1  = A0 + PLANE;                // total 3.93 MB of d_ws

  hipLaunchKernelGGL(pcmd_prep, dim3(320), dim3(256), 0, stream, X, W, Xbf, A0, A1);
  hipLaunchKernelGGL(pcmd_gemm, dim3(16, 16), dim3(256), 0, stream, Xbf, A0, A1, b, out);
}